// Round 8
// baseline (166.031 us; speedup 1.0000x reference)
//
#include <hip/hip_runtime.h>
#include <stdint.h>
#include <math.h>

#define B_ 2
#define S_ 2048
#define D_ 1024
#define H_ 16
#define HD_ 64
#define KVBLK 64

typedef __bf16 bf16_t;
typedef __bf16 bf16x4 __attribute__((ext_vector_type(4)));
typedef __bf16 bf16x8 __attribute__((ext_vector_type(8)));
typedef float f32x4 __attribute__((ext_vector_type(4)));
typedef float f32x16 __attribute__((ext_vector_type(16)));
typedef float float4v __attribute__((ext_vector_type(4)));

#define L2E 1.4426950408889634f
#define NINF (-__builtin_inff())

__device__ __forceinline__ void gload_lds16(const bf16_t* g, bf16_t* l) {
  __builtin_amdgcn_global_load_lds((const __attribute__((address_space(1))) void*)g,
                                   (__attribute__((address_space(3))) void*)l, 16, 0, 0);
}

__device__ __forceinline__ uint32_t packbf(float a, float b) {
  union { __bf16 h[2]; uint32_t u; } cvt;
  cvt.h[0] = (__bf16)a; cvt.h[1] = (__bf16)b;
  return cvt.u;
}

// ---------------- cast f32 -> bf16 (vector x4) ----------------
__global__ void cast_bf16_kernel(const float* __restrict__ src, bf16_t* __restrict__ dst, int n4) {
  int i = blockIdx.x * blockDim.x + threadIdx.x;
  int stride = gridDim.x * blockDim.x;
  for (; i < n4; i += stride) {
    float4v f = *(const float4v*)(src + (size_t)i * 4);
    bf16x4 o;
    o[0] = (__bf16)f[0]; o[1] = (__bf16)f[1]; o[2] = (__bf16)f[2]; o[3] = (__bf16)f[3];
    *(bf16x4*)(dst + (size_t)i * 4) = o;
  }
}

// ---------------- GEMM: C[m][n] = sum_k A[m][k] * B[n][k] ----------------
template <typename OutT>
__global__ __launch_bounds__(256) void gemm_bt(const bf16_t* __restrict__ A,
                                               const bf16_t* __restrict__ Bm,
                                               OutT* __restrict__ C,
                                               int M, int N, int K) {
  __shared__ bf16_t As[128 * 32];
  __shared__ bf16_t Bs[128 * 32];
  const int t = threadIdx.x;
  const int lane = t & 63, wave = t >> 6;
  const int wr = wave >> 1, wc = wave & 1;
  const int qr = lane & 15, g = lane >> 4;
  const int bm = blockIdx.x, bn = blockIdx.y;

  f32x4 acc[4][4];
#pragma unroll
  for (int m = 0; m < 4; m++)
#pragma unroll
    for (int n = 0; n < 4; n++) acc[m][n] = (f32x4){0.f, 0.f, 0.f, 0.f};

  const bf16_t* Abase = A + (size_t)(bm * 128) * K;
  const bf16_t* Bbase = Bm + (size_t)(bn * 128) * K;
  const int srow = t >> 2;
  const int scol = (t & 3) * 8;

  for (int kk = 0; kk < K; kk += 32) {
    gload_lds16(Abase + (size_t)srow * K + kk + scol,        As + t * 8);
    gload_lds16(Abase + (size_t)(srow + 64) * K + kk + scol, As + 2048 + t * 8);
    gload_lds16(Bbase + (size_t)srow * K + kk + scol,        Bs + t * 8);
    gload_lds16(Bbase + (size_t)(srow + 64) * K + kk + scol, Bs + 2048 + t * 8);
    __syncthreads();
    bf16x8 a[4], b[4];
#pragma unroll
    for (int m = 0; m < 4; m++)
      a[m] = *(const bf16x8*)(As + (wr * 64 + m * 16 + qr) * 32 + g * 8);
#pragma unroll
    for (int n = 0; n < 4; n++)
      b[n] = *(const bf16x8*)(Bs + (wc * 64 + n * 16 + qr) * 32 + g * 8);
#pragma unroll
    for (int m = 0; m < 4; m++)
#pragma unroll
      for (int n = 0; n < 4; n++)
        acc[m][n] = __builtin_amdgcn_mfma_f32_16x16x32_bf16(a[m], b[n], acc[m][n], 0, 0, 0);
    __syncthreads();
  }

#pragma unroll
  for (int m = 0; m < 4; m++) {
    int row0 = bm * 128 + wr * 64 + m * 16 + g * 4;
#pragma unroll
    for (int n = 0; n < 4; n++) {
      int col = bn * 128 + wc * 64 + n * 16 + qr;
#pragma unroll
      for (int r = 0; r < 4; r++)
        C[(size_t)(row0 + r) * N + col] = (OutT)acc[m][n][r];
    }
  }
}

// ---------------- RoPE on q,k + q-scale; writes Q,K as [B][H][S][HD] bf16 ----------------
__global__ void rope_qk_kernel(const bf16_t* __restrict__ qkv, const int* __restrict__ pos,
                               bf16_t* __restrict__ Q, bf16_t* __restrict__ Ko) {
  int idx = blockIdx.x * blockDim.x + threadIdx.x;
  if (idx >= B_ * S_ * H_ * 32) return;
  int i = idx & 31;
  int h = (idx >> 5) & (H_ - 1);
  int bs = idx >> 9;
  const bf16_t* row = qkv + (size_t)bs * (3 * D_) + h * 192;
  float q1 = (float)row[i], q2 = (float)row[i + 32];
  float k1 = (float)row[64 + i], k2 = (float)row[96 + i];
  int p = pos[bs];
  float inv = exp2f(-(float)i * (13.287712379549449f / 32.0f));
  float ang = (float)p * inv;
  float sn, cs;
  sincosf(ang, &sn, &cs);
  float qo1 = (q1 * cs - q2 * sn) * 0.125f;
  float qo2 = (q2 * cs + q1 * sn) * 0.125f;
  float ko1 = k1 * cs - k2 * sn;
  float ko2 = k2 * cs + k1 * sn;
  int b = bs >> 11, s = bs & (S_ - 1);
  size_t o = ((size_t)(b * H_ + h) * S_ + s) * HD_ + i;
  Q[o] = (__bf16)qo1;  Q[o + 32] = (__bf16)qo2;
  Ko[o] = (__bf16)ko1; Ko[o + 32] = (__bf16)ko2;
}

// ---------------- V transpose: qkv v-slice -> Vt [B][H][HD][S] bf16 ----------------
__global__ __launch_bounds__(256) void v_transpose_kernel(const bf16_t* __restrict__ qkv,
                                                          bf16_t* __restrict__ Vt) {
  __shared__ bf16_t tile[64][72];
  int t = threadIdx.x;
  int s0 = blockIdx.x * 64;
  int h = blockIdx.y, b = blockIdx.z;
  int sl = t >> 4;
  int cb = (t & 15) * 4;
#pragma unroll
  for (int it = 0; it < 4; it++) {
    int s = sl + it * 16;
    const bf16_t* src = qkv + (size_t)(b * S_ + s0 + s) * (3 * D_) + h * 192 + 128 + cb;
    bf16x4 v = *(const bf16x4*)src;
    tile[cb + 0][s] = v[0]; tile[cb + 1][s] = v[1];
    tile[cb + 2][s] = v[2]; tile[cb + 3][s] = v[3];
  }
  __syncthreads();
#pragma unroll
  for (int it = 0; it < 4; it++) {
    int d = sl + it * 16;
    bf16x4 v;
    v[0] = tile[d][cb]; v[1] = tile[d][cb + 1]; v[2] = tile[d][cb + 2]; v[3] = tile[d][cb + 3];
    *(bf16x4*)(Vt + ((size_t)((b * H_ + h) * HD_ + d)) * S_ + s0 + cb) = v;
  }
}

// ---------------- flash attention: 2-wave LDS-dbuf blocks + XCD-resident KV mapping ----------------
// 1-D grid of 1024, 128 threads = 2 waves; block owns 64 q-rows; wave wv owns 32.
// bid -> XCD is round-robin (bid & 7, m09); each (b,h)'s 32 q-blocks pinned to ONE XCD
// so its 512 KB KV stays L2-resident (4 bh x 512 KB = 2 MB < 4 MB per-XCD L2):
//   bh   = (bid & 7) * 4 + ((bid >> 3) & 3)
//   qblk = 31 - (bid >> 5)            // heavy q-blocks dispatch first
// 32 KB LDS/block -> 5 blocks/CU -> 10 resident waves/CU (2.5x the R7 grid-limited level).
__global__ __launch_bounds__(128) void attn_kernel(const bf16_t* __restrict__ Q,
                                                   const bf16_t* __restrict__ K,
                                                   const bf16_t* __restrict__ Vt,
                                                   const int* __restrict__ pos,
                                                   bf16_t* __restrict__ O) {
  __shared__ bf16_t Ks[2][64 * 64];   // [buf][k][d] 16B-chunk XOR swizzled
  __shared__ bf16_t Vs[2][64 * 64];   // [buf][d][s] 16B-chunk XOR swizzled

  const int t = threadIdx.x;
  const int lane = t & 63, wv = t >> 6;
  const int l31 = lane & 31, hi = lane >> 5;

  const int bid = blockIdx.x;
  const int bh = (bid & 7) * 4 + ((bid >> 3) & 3);
  const int qblk = 31 - (bid >> 5);
  const int b = bh >> 4, h = bh & 15;
  const int q0 = qblk * 64;

  const bf16_t* Qb = Q + (size_t)bh * (S_ * HD_);
  const bf16_t* Kb = K + (size_t)bh * (S_ * HD_);
  const bf16_t* Vb = Vt + (size_t)bh * (HD_ * S_);

  // Q fragments (B-operand): lane holds row q = q0+wv*32+l31, d = c*16 + 8*hi + j
  const int qrow = q0 + wv * 32 + l31;
  bf16x8 qf[4];
#pragma unroll
  for (int c = 0; c < 4; c++)
    qf[c] = *(const bf16x8*)(Qb + (size_t)qrow * HD_ + c * 16 + hi * 8);

  const int prow = pos[b * S_ + qrow];
  int wmin = prow;
#pragma unroll
  for (int off = 1; off < 32; off <<= 1) wmin = min(wmin, __shfl_xor(wmin, off));

  // block-wide max position over the 64 q-rows (same result in both waves)
  int mp = pos[b * S_ + q0 + lane];
#pragma unroll
  for (int off = 1; off < 64; off <<= 1) mp = max(mp, __shfl_xor(mp, off));
  const int ntiles = min(S_ / KVBLK, (mp >> 6) + 1);

  // staging: 128 threads x 4 chunks of 16B per 8KB tile; e&7 == t&7 for all 4
  const int c0 = t & 7;
  const int r0 = t >> 3, r1 = (t + 128) >> 3, r2 = (t + 256) >> 3, r3 = (t + 384) >> 3;
  const bf16_t* Kg0 = Kb + (size_t)r0 * HD_ + ((c0 ^ (r0 & 7)) * 8);
  const bf16_t* Kg1 = Kb + (size_t)r1 * HD_ + ((c0 ^ (r1 & 7)) * 8);
  const bf16_t* Kg2 = Kb + (size_t)r2 * HD_ + ((c0 ^ (r2 & 7)) * 8);
  const bf16_t* Kg3 = Kb + (size_t)r3 * HD_ + ((c0 ^ (r3 & 7)) * 8);
  const bf16_t* Vg0 = Vb + (size_t)r0 * S_ + ((c0 ^ (r0 & 7)) * 8);
  const bf16_t* Vg1 = Vb + (size_t)r1 * S_ + ((c0 ^ (r1 & 7)) * 8);
  const bf16_t* Vg2 = Vb + (size_t)r2 * S_ + ((c0 ^ (r2 & 7)) * 8);
  const bf16_t* Vg3 = Vb + (size_t)r3 * S_ + ((c0 ^ (r3 & 7)) * 8);
  const int ld0 = t * 8, ld1 = (t + 128) * 8, ld2 = (t + 256) * 8, ld3 = (t + 384) * 8;

  f32x16 oT[2];
#pragma unroll
  for (int dt = 0; dt < 2; dt++)
#pragma unroll
    for (int r = 0; r < 16; r++) oT[dt][r] = 0.f;
  float m_run = NINF, l_run = 0.f;

  // prologue: stage tile 0 into buf 0
  gload_lds16(Kg0, Ks[0] + ld0); gload_lds16(Kg1, Ks[0] + ld1);
  gload_lds16(Kg2, Ks[0] + ld2); gload_lds16(Kg3, Ks[0] + ld3);
  gload_lds16(Vg0, Vs[0] + ld0); gload_lds16(Vg1, Vs[0] + ld1);
  gload_lds16(Vg2, Vs[0] + ld2); gload_lds16(Vg3, Vs[0] + ld3);
  __syncthreads();

  for (int kt = 0; kt < ntiles; ++kt) {
    const int k0 = kt * KVBLK;
    const int cur = kt & 1;
    if (kt + 1 < ntiles) {
      const int kn = (kt + 1) * KVBLK;
      const size_t kof = (size_t)kn * HD_;
      gload_lds16(Kg0 + kof, Ks[cur ^ 1] + ld0); gload_lds16(Kg1 + kof, Ks[cur ^ 1] + ld1);
      gload_lds16(Kg2 + kof, Ks[cur ^ 1] + ld2); gload_lds16(Kg3 + kof, Ks[cur ^ 1] + ld3);
      gload_lds16(Vg0 + kn, Vs[cur ^ 1] + ld0);  gload_lds16(Vg1 + kn, Vs[cur ^ 1] + ld1);
      gload_lds16(Vg2 + kn, Vs[cur ^ 1] + ld2);  gload_lds16(Vg3 + kn, Vs[cur ^ 1] + ld3);
    }
    const bf16_t* Kc = Ks[cur];
    const bf16_t* Vc = Vs[cur];

    // QK^T swapped
    f32x16 s0, s1;
#pragma unroll
    for (int r = 0; r < 16; r++) { s0[r] = 0.f; s1[r] = 0.f; }
    __builtin_amdgcn_s_setprio(1);
#pragma unroll
    for (int c = 0; c < 4; c++) {
      const int c2 = c * 2 + hi;
      const int kr0 = l31;
      const int kr1 = 32 + l31;
      bf16x8 kf0 = *(const bf16x8*)(Kc + kr0 * 64 + ((c2 ^ (kr0 & 7)) * 8));
      bf16x8 kf1 = *(const bf16x8*)(Kc + kr1 * 64 + ((c2 ^ (kr1 & 7)) * 8));
      s0 = __builtin_amdgcn_mfma_f32_32x32x16_bf16(kf0, qf[c], s0, 0, 0, 0);
      s1 = __builtin_amdgcn_mfma_f32_32x32x16_bf16(kf1, qf[c], s1, 0, 0, 0);
    }
    __builtin_amdgcn_s_setprio(0);

    // mask (skip when tile fully visible for this wave)
    float p0[16], p1[16];
    if (k0 + 63 > wmin) {
#pragma unroll
      for (int r = 0; r < 16; r++) {
        int koff = (r & 3) + 8 * (r >> 2) + 4 * hi;
        p0[r] = (k0 + koff <= prow) ? s0[r] : NINF;
        p1[r] = (k0 + 32 + koff <= prow) ? s1[r] : NINF;
      }
    } else {
#pragma unroll
      for (int r = 0; r < 16; r++) { p0[r] = s0[r]; p1[r] = s1[r]; }
    }

    // per-lane online softmax with defer-max (T13, THR=8)
    float tm = NINF;
#pragma unroll
    for (int r = 0; r < 16; r++) tm = fmaxf(tm, fmaxf(p0[r], p1[r]));
    tm = fmaxf(tm, __shfl_xor(tm, 32));
    if (__any(tm > m_run + 8.0f)) {
      float mn = fmaxf(fmaxf(m_run, tm), -1e30f);
      float scale = exp2f((m_run - mn) * L2E);
      l_run *= scale;
#pragma unroll
      for (int dt = 0; dt < 2; dt++)
#pragma unroll
        for (int r = 0; r < 16; r++) oT[dt][r] *= scale;
      m_run = mn;
    }
    const float mnl = m_run * L2E;
    float rs = 0.f;
#pragma unroll
    for (int r = 0; r < 16; r++) {
      p0[r] = exp2f(p0[r] * L2E - mnl);
      p1[r] = exp2f(p1[r] * L2E - mnl);
      rs += p0[r] + p1[r];
    }
    rs += __shfl_xor(rs, 32);
    l_run += rs;

    // PV swapped: oT[dt] += V^T(32d x 16k) x P(16k x 32q)
#pragma unroll
    for (int kc = 0; kc < 4; kc++) {
      const float* P = (kc < 2) ? p0 : p1;
      const int rb = (kc & 1) * 8;
      uint32_t xa0 = packbf(P[rb + 0], P[rb + 1]);
      uint32_t xa1 = packbf(P[rb + 2], P[rb + 3]);
      uint32_t xb0 = packbf(P[rb + 4], P[rb + 5]);
      uint32_t xb1 = packbf(P[rb + 6], P[rb + 7]);
      uint32_t sa0 = (uint32_t)__shfl_xor((int)xa0, 32);
      uint32_t sa1 = (uint32_t)__shfl_xor((int)xa1, 32);
      uint32_t sb0 = (uint32_t)__shfl_xor((int)xb0, 32);
      uint32_t sb1 = (uint32_t)__shfl_xor((int)xb1, 32);
      union { uint32_t u[4]; bf16x8 v; } pf;
      pf.u[0] = hi ? sb0 : xa0;
      pf.u[1] = hi ? sb1 : xa1;
      pf.u[2] = hi ? xb0 : sa0;
      pf.u[3] = hi ? xb1 : sa1;
      __builtin_amdgcn_s_setprio(1);
#pragma unroll
      for (int dt = 0; dt < 2; dt++) {
        const int vr = dt * 32 + l31;
        const int c2 = kc * 2 + hi;
        bf16x8 vf = *(const bf16x8*)(Vc + vr * 64 + ((c2 ^ (vr & 7)) * 8));
        oT[dt] = __builtin_amdgcn_mfma_f32_32x32x16_bf16(vf, pf.v, oT[dt], 0, 0, 0);
      }
      __builtin_amdgcn_s_setprio(0);
    }

    __syncthreads();  // drains this iter's prefetch (issued pre-compute) + joins waves
  }

  // epilogue: O^T (regs) -> LDS transpose -> coalesced global stores
  const float rl = (l_run > 0.f) ? 1.0f / l_run : 0.f;
  bf16_t* Ot = (bf16_t*)Ks + wv * 2048;  // 2 waves x [32 q][64 d] swizzled = 8KB
#pragma unroll
  for (int dt = 0; dt < 2; dt++)
#pragma unroll
    for (int r = 0; r < 16; r++) {
      int chunk = dt * 4 + (r >> 2);
      int el = (r & 3) + 4 * hi;
      Ot[l31 * 64 + ((chunk ^ (l31 & 7)) * 8) + el] = (__bf16)(oT[dt][r] * rl);
    }
  __syncthreads();
#pragma unroll
  for (int it = 0; it < 4; it++) {
    int qr2 = (lane >> 3) + it * 8;
    int cc = lane & 7;
    bf16x8 v = *(const bf16x8*)(Ot + qr2 * 64 + ((cc ^ (qr2 & 7)) * 8));
    *(bf16x8*)(&O[(size_t)(b * S_ + q0 + wv * 32 + qr2) * D_ + h * 64 + cc * 8]) = v;
  }
}

extern "C" void kernel_launch(void* const* d_in, const int* in_sizes, int n_in,
                              void* d_out, int out_size, void* d_ws, size_t ws_size,
                              hipStream_t stream) {
  const float* inputs = (const float*)d_in[0];
  const int* positions = (const int*)d_in[1];
  const float* W_in = (const float*)d_in[2];
  const float* W_out = (const float*)d_in[3];
  float* out = (float*)d_out;

  bf16_t* X_bf = (bf16_t*)d_ws;
  bf16_t* Win_bf = X_bf + (size_t)4096 * 1024;
  bf16_t* Wout_bf = Win_bf + (size_t)3072 * 1024;
  bf16_t* qkv_bf = Wout_bf + (size_t)1024 * 1024;
  bf16_t* Qb = qkv_bf + (size_t)4096 * 3072;
  bf16_t* Kb = Qb + (size_t)B_ * H_ * S_ * HD_;
  bf16_t* Vtb = Kb + (size_t)B_ * H_ * S_ * HD_;
  bf16_t* Ob = Vtb + (size_t)B_ * H_ * S_ * HD_;

  cast_bf16_kernel<<<dim3(2048), dim3(256), 0, stream>>>(inputs, X_bf, (4096 * 1024) / 4);
  cast_bf16_kernel<<<dim3(2048), dim3(256), 0, stream>>>(W_in, Win_bf, (3072 * 1024) / 4);
  cast_bf16_kernel<<<dim3(1024), dim3(256), 0, stream>>>(W_out, Wout_bf, (1024 * 1024) / 4);

  gemm_bt<bf16_t><<<dim3(32, 24), dim3(256), 0, stream>>>(X_bf, Win_bf, qkv_bf, 4096, 3072, 1024);

  rope_qk_kernel<<<dim3((B_ * S_ * H_ * 32) / 256), dim3(256), 0, stream>>>(qkv_bf, positions, Qb, Kb);
  v_transpose_kernel<<<dim3(S_ / 64, H_, B_), dim3(256), 0, stream>>>(qkv_bf, Vtb);

  attn_kernel<<<dim3(1024), dim3(128), 0, stream>>>(Qb, Kb, Vtb, positions, Ob);

  gemm_bt<float><<<dim3(32, 8), dim3(256), 0, stream>>>(Ob, Wout_bf, out, 4096, 1024, 1024);
}

// Round 10
// 160.116 us; speedup vs baseline: 1.0369x; 1.0369x over previous
//
#include <hip/hip_runtime.h>
#include <stdint.h>
#include <math.h>

#define B_ 2
#define S_ 2048
#define D_ 1024
#define H_ 16
#define HD_ 64
#define KVBLK 64

typedef __bf16 bf16_t;
typedef __bf16 bf16x4 __attribute__((ext_vector_type(4)));
typedef __bf16 bf16x8 __attribute__((ext_vector_type(8)));
typedef float f32x4 __attribute__((ext_vector_type(4)));
typedef float f32x16 __attribute__((ext_vector_type(16)));
typedef float float4v __attribute__((ext_vector_type(4)));

#define L2E 1.4426950408889634f
#define NINF (-__builtin_inff())

__device__ __forceinline__ void gload_lds16(const bf16_t* g, bf16_t* l) {
  __builtin_amdgcn_global_load_lds((const __attribute__((address_space(1))) void*)g,
                                   (__attribute__((address_space(3))) void*)l, 16, 0, 0);
}

__device__ __forceinline__ uint32_t packbf(float a, float b) {
  union { __bf16 h[2]; uint32_t u; } cvt;
  cvt.h[0] = (__bf16)a; cvt.h[1] = (__bf16)b;
  return cvt.u;
}

// ---------------- cast f32 -> bf16 (vector x4) ----------------
__global__ void cast_bf16_kernel(const float* __restrict__ src, bf16_t* __restrict__ dst, int n4) {
  int i = blockIdx.x * blockDim.x + threadIdx.x;
  int stride = gridDim.x * blockDim.x;
  for (; i < n4; i += stride) {
    float4v f = *(const float4v*)(src + (size_t)i * 4);
    bf16x4 o;
    o[0] = (__bf16)f[0]; o[1] = (__bf16)f[1]; o[2] = (__bf16)f[2]; o[3] = (__bf16)f[3];
    *(bf16x4*)(dst + (size_t)i * 4) = o;
  }
}

// ---------------- small GEMM (128^2, m97 structure) for gemm2 ----------------
template <typename OutT>
__global__ __launch_bounds__(256) void gemm_bt(const bf16_t* __restrict__ A,
                                               const bf16_t* __restrict__ Bm,
                                               OutT* __restrict__ C,
                                               int M, int N, int K) {
  __shared__ bf16_t As[128 * 32];
  __shared__ bf16_t Bs[128 * 32];
  const int t = threadIdx.x;
  const int lane = t & 63, wave = t >> 6;
  const int wr = wave >> 1, wc = wave & 1;
  const int qr = lane & 15, g = lane >> 4;
  const int bm = blockIdx.x, bn = blockIdx.y;

  f32x4 acc[4][4];
#pragma unroll
  for (int m = 0; m < 4; m++)
#pragma unroll
    for (int n = 0; n < 4; n++) acc[m][n] = (f32x4){0.f, 0.f, 0.f, 0.f};

  const bf16_t* Abase = A + (size_t)(bm * 128) * K;
  const bf16_t* Bbase = Bm + (size_t)(bn * 128) * K;
  const int srow = t >> 2;
  const int scol = (t & 3) * 8;

  for (int kk = 0; kk < K; kk += 32) {
    gload_lds16(Abase + (size_t)srow * K + kk + scol,        As + t * 8);
    gload_lds16(Abase + (size_t)(srow + 64) * K + kk + scol, As + 2048 + t * 8);
    gload_lds16(Bbase + (size_t)srow * K + kk + scol,        Bs + t * 8);
    gload_lds16(Bbase + (size_t)(srow + 64) * K + kk + scol, Bs + 2048 + t * 8);
    __syncthreads();
    bf16x8 a[4], b[4];
#pragma unroll
    for (int m = 0; m < 4; m++)
      a[m] = *(const bf16x8*)(As + (wr * 64 + m * 16 + qr) * 32 + g * 8);
#pragma unroll
    for (int n = 0; n < 4; n++)
      b[n] = *(const bf16x8*)(Bs + (wc * 64 + n * 16 + qr) * 32 + g * 8);
#pragma unroll
    for (int m = 0; m < 4; m++)
#pragma unroll
      for (int n = 0; n < 4; n++)
        acc[m][n] = __builtin_amdgcn_mfma_f32_16x16x32_bf16(a[m], b[n], acc[m][n], 0, 0, 0);
    __syncthreads();
  }

#pragma unroll
  for (int m = 0; m < 4; m++) {
    int row0 = bm * 128 + wr * 64 + m * 16 + g * 4;
#pragma unroll
    for (int n = 0; n < 4; n++) {
      int col = bn * 128 + wc * 64 + n * 16 + qr;
#pragma unroll
      for (int r = 0; r < 4; r++)
        C[(size_t)(row0 + r) * N + col] = (OutT)acc[m][n][r];
    }
  }
}

// ---------------- big GEMM: 256^2 tile, BK=64, 8-wave, phase-pipelined (T3+T4+T5) ----------------
// Region-read map (A tile, rows): region0=0..63 & region2=128..191 read in ph0 (alo, wm=0/1);
// region1=64..127 & region3=192..255 read in ph2 (ahi). B rows all read by end of ph1.
// Staging of tile T+2 into the SAME buffer, region-by-region AFTER each region's reads complete:
//   ph1: A regions {0,2}; ph2: B all; ph3: A regions {1,3}.   (R9 bug: staged {0,1} in ph1 ->
//   overwrote region1 before ph2's ahi read. Fixed.)
// Gate: counted vmcnt(8) -- tile T's 8 loads complete, tile T+1's 8 stay in flight (m218).
template <typename OutT>
__global__ __launch_bounds__(512, 2) void gemm256(const bf16_t* __restrict__ A,
                                                  const bf16_t* __restrict__ Bm,
                                                  OutT* __restrict__ C,
                                                  int M, int N, int K) {
  __shared__ bf16_t As[2][256 * 64];
  __shared__ bf16_t Bs[2][256 * 64];
  const int t = threadIdx.x;
  const int lane = t & 63, wid = t >> 6;
  const int qr = lane & 15, g = lane >> 4;
  const int wm = wid >> 2, wn = wid & 3;
  const int bm = blockIdx.x, bn = blockIdx.y;
  const int NT = K >> 6;

  const bf16_t* Ab = A + (size_t)(bm * 256) * K;
  const bf16_t* Bb = Bm + (size_t)(bn * 256) * K;

  // staging map: 2048 16B-chunks per 32KB tile; thread stages e = t + 512*i, i=0..3.
  // LDS chunk (row=e>>3, cs=e&7) holds global col-chunk cs^(row&7)  (XOR involution, both sides).
  const bf16_t* srcA[4];
  const bf16_t* srcB[4];
  int ldsOff[4];
#pragma unroll
  for (int i = 0; i < 4; i++) {
    int e = t + 512 * i;
    int row = e >> 3, cs = e & 7;
    int gcol = (cs ^ (row & 7)) * 8;
    srcA[i] = Ab + (size_t)row * K + gcol;
    srcB[i] = Bb + (size_t)row * K + gcol;
    ldsOff[i] = e * 8;
  }

  f32x4 acc[8][4];
#pragma unroll
  for (int m = 0; m < 8; m++)
#pragma unroll
    for (int n = 0; n < 4; n++) acc[m][n] = (f32x4){0.f, 0.f, 0.f, 0.f};

// swizzled ds_read of one 16B frag: row r, k-slot k
#define RD(buf_, r_, k_) (*(const bf16x8*)((buf_) + (r_) * 64 + ((((k_) * 4 + g) ^ ((r_) & 7)) * 8)))

  // prologue: stage tiles 0 and 1 (16 issues/thread; tile0's 8 are oldest)
#pragma unroll
  for (int i = 0; i < 4; i++) gload_lds16(srcA[i], As[0] + ldsOff[i]);
#pragma unroll
  for (int i = 0; i < 4; i++) gload_lds16(srcB[i], Bs[0] + ldsOff[i]);
#pragma unroll
  for (int i = 0; i < 4; i++) gload_lds16(srcA[i] + 64, As[1] + ldsOff[i]);
#pragma unroll
  for (int i = 0; i < 4; i++) gload_lds16(srcB[i] + 64, Bs[1] + ldsOff[i]);

  for (int T = 0; T < NT; ++T) {
    bf16_t* A_c = As[T & 1];
    bf16_t* B_c = Bs[T & 1];
    // gate: tile T's loads complete; tile T+1's (newest 8) stay in flight
    if (T + 1 < NT) asm volatile("s_waitcnt vmcnt(8)" ::: "memory");
    else            asm volatile("s_waitcnt vmcnt(0)" ::: "memory");
    __builtin_amdgcn_sched_barrier(0);
    __builtin_amdgcn_s_barrier();

    const bool st = (T + 2 < NT);
    const int kt2 = (T + 2) * 64;

    bf16x8 alo[4][2], ahi[4][2], bfr[4][2];

    // ---- ph0: read a_lo (regions 0,2) + b01; MFMA m0-3 x n0-1 ----
#pragma unroll
    for (int m = 0; m < 4; m++) {
      int r = wm * 128 + m * 16 + qr;
      alo[m][0] = RD(A_c, r, 0); alo[m][1] = RD(A_c, r, 1);
    }
#pragma unroll
    for (int n = 0; n < 2; n++) {
      int r = wn * 64 + n * 16 + qr;
      bfr[n][0] = RD(B_c, r, 0); bfr[n][1] = RD(B_c, r, 1);
    }
    __builtin_amdgcn_s_barrier();
    __builtin_amdgcn_s_setprio(1);
#pragma unroll
    for (int m = 0; m < 4; m++)
#pragma unroll
      for (int n = 0; n < 2; n++)
#pragma unroll
        for (int k = 0; k < 2; k++)
          acc[m][n] = __builtin_amdgcn_mfma_f32_16x16x32_bf16(alo[m][k], bfr[n][k], acc[m][n], 0, 0, 0);
    __builtin_amdgcn_s_setprio(0);
    __builtin_amdgcn_s_barrier();

    // ---- ph1: read b23; stage T+2 A regions {0,2} (freed by ph0); MFMA m0-3 x n2-3 ----
#pragma unroll
    for (int n = 2; n < 4; n++) {
      int r = wn * 64 + n * 16 + qr;
      bfr[n][0] = RD(B_c, r, 0); bfr[n][1] = RD(B_c, r, 1);
    }
    if (st) {
      gload_lds16(srcA[0] + kt2, A_c + ldsOff[0]);
      gload_lds16(srcA[2] + kt2, A_c + ldsOff[2]);
    }
    __builtin_amdgcn_s_barrier();
    __builtin_amdgcn_s_setprio(1);
#pragma unroll
    for (int m = 0; m < 4; m++)
#pragma unroll
      for (int n = 2; n < 4; n++)
#pragma unroll
        for (int k = 0; k < 2; k++)
          acc[m][n] = __builtin_amdgcn_mfma_f32_16x16x32_bf16(alo[m][k], bfr[n][k], acc[m][n], 0, 0, 0);
    __builtin_amdgcn_s_setprio(0);
    __builtin_amdgcn_s_barrier();

    // ---- ph2: read a_hi (regions 1,3); stage T+2 B (all B reads done by end of ph1); MFMA m4-7 x n0-1 ----
#pragma unroll
    for (int m = 0; m < 4; m++) {
      int r = wm * 128 + (m + 4) * 16 + qr;
      ahi[m][0] = RD(A_c, r, 0); ahi[m][1] = RD(A_c, r, 1);
    }
    if (st) {
      gload_lds16(srcB[0] + kt2, B_c + ldsOff[0]);
      gload_lds16(srcB[1] + kt2, B_c + ldsOff[1]);
      gload_lds16(srcB[2] + kt2, B_c + ldsOff[2]);
      gload_lds16(srcB[3] + kt2, B_c + ldsOff[3]);
    }
    __builtin_amdgcn_s_barrier();
    __builtin_amdgcn_s_setprio(1);
#pragma unroll
    for (int m = 0; m < 4; m++)
#pragma unroll
      for (int n = 0; n < 2; n++)
#pragma unroll
        for (int k = 0; k < 2; k++)
          acc[m + 4][n] = __builtin_amdgcn_mfma_f32_16x16x32_bf16(ahi[m][k], bfr[n][k], acc[m + 4][n], 0, 0, 0);
    __builtin_amdgcn_s_setprio(0);
    __builtin_amdgcn_s_barrier();

    // ---- ph3: stage T+2 A regions {1,3} (freed by ph2); MFMA m4-7 x n2-3 ----
    if (st) {
      gload_lds16(srcA[1] + kt2, A_c + ldsOff[1]);
      gload_lds16(srcA[3] + kt2, A_c + ldsOff[3]);
    }
    __builtin_amdgcn_s_barrier();
    __builtin_amdgcn_s_setprio(1);
#pragma unroll
    for (int m = 0; m < 4; m++)
#pragma unroll
      for (int n = 2; n < 4; n++)
#pragma unroll
        for (int k = 0; k < 2; k++)
          acc[m + 4][n] = __builtin_amdgcn_mfma_f32_16x16x32_bf16(ahi[m][k], bfr[n][k], acc[m + 4][n], 0, 0, 0);
    __builtin_amdgcn_s_setprio(0);
    __builtin_amdgcn_s_barrier();
  }
#undef RD

  // epilogue
#pragma unroll
  for (int m = 0; m < 8; m++) {
    int row0 = bm * 256 + wm * 128 + m * 16 + g * 4;
#pragma unroll
    for (int n = 0; n < 4; n++) {
      int col = bn * 256 + wn * 64 + n * 16 + qr;
#pragma unroll
      for (int r = 0; r < 4; r++)
        C[(size_t)(row0 + r) * N + col] = (OutT)acc[m][n][r];
    }
  }
}

// ---------------- RoPE on q,k + q-scale; writes Q,K as [B][H][S][HD] bf16 ----------------
__global__ void rope_qk_kernel(const bf16_t* __restrict__ qkv, const int* __restrict__ pos,
                               bf16_t* __restrict__ Q, bf16_t* __restrict__ Ko) {
  int idx = blockIdx.x * blockDim.x + threadIdx.x;
  if (idx >= B_ * S_ * H_ * 32) return;
  int i = idx & 31;
  int h = (idx >> 5) & (H_ - 1);
  int bs = idx >> 9;
  const bf16_t* row = qkv + (size_t)bs * (3 * D_) + h * 192;
  float q1 = (float)row[i], q2 = (float)row[i + 32];
  float k1 = (float)row[64 + i], k2 = (float)row[96 + i];
  int p = pos[bs];
  float inv = exp2f(-(float)i * (13.287712379549449f / 32.0f));
  float ang = (float)p * inv;
  float sn, cs;
  sincosf(ang, &sn, &cs);
  float qo1 = (q1 * cs - q2 * sn) * 0.125f;
  float qo2 = (q2 * cs + q1 * sn) * 0.125f;
  float ko1 = k1 * cs - k2 * sn;
  float ko2 = k2 * cs + k1 * sn;
  int b = bs >> 11, s = bs & (S_ - 1);
  size_t o = ((size_t)(b * H_ + h) * S_ + s) * HD_ + i;
  Q[o] = (__bf16)qo1;  Q[o + 32] = (__bf16)qo2;
  Ko[o] = (__bf16)ko1; Ko[o + 32] = (__bf16)ko2;
}

// ---------------- V transpose: qkv v-slice -> Vt [B][H][HD][S] bf16 ----------------
__global__ __launch_bounds__(256) void v_transpose_kernel(const bf16_t* __restrict__ qkv,
                                                          bf16_t* __restrict__ Vt) {
  __shared__ bf16_t tile[64][72];
  int t = threadIdx.x;
  int s0 = blockIdx.x * 64;
  int h = blockIdx.y, b = blockIdx.z;
  int sl = t >> 4;
  int cb = (t & 15) * 4;
#pragma unroll
  for (int it = 0; it < 4; it++) {
    int s = sl + it * 16;
    const bf16_t* src = qkv + (size_t)(b * S_ + s0 + s) * (3 * D_) + h * 192 + 128 + cb;
    bf16x4 v = *(const bf16x4*)src;
    tile[cb + 0][s] = v[0]; tile[cb + 1][s] = v[1];
    tile[cb + 2][s] = v[2]; tile[cb + 3][s] = v[3];
  }
  __syncthreads();
#pragma unroll
  for (int it = 0; it < 4; it++) {
    int d = sl + it * 16;
    bf16x4 v;
    v[0] = tile[d][cb]; v[1] = tile[d][cb + 1]; v[2] = tile[d][cb + 2]; v[3] = tile[d][cb + 3];
    *(bf16x4*)(Vt + ((size_t)((b * H_ + h) * HD_ + d)) * S_ + s0 + cb) = v;
  }
}

// ---------------- flash attention: 4-wave LDS-dbuf + XCD-resident KV mapping (R7, proven) ----------------
__global__ __launch_bounds__(256) void attn_kernel(const bf16_t* __restrict__ Q,
                                                   const bf16_t* __restrict__ K,
                                                   const bf16_t* __restrict__ Vt,
                                                   const int* __restrict__ pos,
                                                   bf16_t* __restrict__ O) {
  __shared__ bf16_t Ks[2][64 * 64];
  __shared__ bf16_t Vs[2][64 * 64];

  const int t = threadIdx.x;
  const int lane = t & 63, wv = t >> 6;
  const int l31 = lane & 31, hi = lane >> 5;

  const int bid = blockIdx.x;
  const int bh = (bid & 7) * 4 + ((bid >> 3) & 3);
  const int qblk = 15 - (bid >> 5);
  const int b = bh >> 4, h = bh & 15;
  const int q0 = qblk * 128;

  const bf16_t* Qb = Q + (size_t)bh * (S_ * HD_);
  const bf16_t* Kb = K + (size_t)bh * (S_ * HD_);
  const bf16_t* Vb = Vt + (size_t)bh * (HD_ * S_);

  const int qrow = q0 + wv * 32 + l31;
  bf16x8 qf[4];
#pragma unroll
  for (int c = 0; c < 4; c++)
    qf[c] = *(const bf16x8*)(Qb + (size_t)qrow * HD_ + c * 16 + hi * 8);

  const int prow = pos[b * S_ + qrow];
  int wmin = prow;
#pragma unroll
  for (int off = 1; off < 32; off <<= 1) wmin = min(wmin, __shfl_xor(wmin, off));

  int mp = max(pos[b * S_ + q0 + lane], pos[b * S_ + q0 + 64 + lane]);
#pragma unroll
  for (int off = 1; off < 64; off <<= 1) mp = max(mp, __shfl_xor(mp, off));
  const int ntiles = min(S_ / KVBLK, (mp >> 6) + 1);

  const int r0 = t >> 3, c0 = t & 7;
  const int r1 = (t + 256) >> 3, c1 = t & 7;
  const bf16_t* KgA = Kb + (size_t)r0 * HD_ + ((c0 ^ (r0 & 7)) * 8);
  const bf16_t* KgB = Kb + (size_t)r1 * HD_ + ((c1 ^ (r1 & 7)) * 8);
  const bf16_t* VgA = Vb + (size_t)r0 * S_ + ((c0 ^ (r0 & 7)) * 8);
  const bf16_t* VgB = Vb + (size_t)r1 * S_ + ((c1 ^ (r1 & 7)) * 8);
  const int ldsA = t * 8, ldsB = (t + 256) * 8;

  f32x16 oT[2];
#pragma unroll
  for (int dt = 0; dt < 2; dt++)
#pragma unroll
    for (int r = 0; r < 16; r++) oT[dt][r] = 0.f;
  float m_run = NINF, l_run = 0.f;

  gload_lds16(KgA, Ks[0] + ldsA);
  gload_lds16(KgB, Ks[0] + ldsB);
  gload_lds16(VgA, Vs[0] + ldsA);
  gload_lds16(VgB, Vs[0] + ldsB);
  __syncthreads();

  for (int kt = 0; kt < ntiles; ++kt) {
    const int k0 = kt * KVBLK;
    const int cur = kt & 1;
    if (kt + 1 < ntiles) {
      const int kn = (kt + 1) * KVBLK;
      gload_lds16(KgA + (size_t)kn * HD_, Ks[cur ^ 1] + ldsA);
      gload_lds16(KgB + (size_t)kn * HD_, Ks[cur ^ 1] + ldsB);
      gload_lds16(VgA + kn, Vs[cur ^ 1] + ldsA);
      gload_lds16(VgB + kn, Vs[cur ^ 1] + ldsB);
    }
    const bf16_t* Kc = Ks[cur];
    const bf16_t* Vc = Vs[cur];

    f32x16 s0, s1;
#pragma unroll
    for (int r = 0; r < 16; r++) { s0[r] = 0.f; s1[r] = 0.f; }
    __builtin_amdgcn_s_setprio(1);
#pragma unroll
    for (int c = 0; c < 4; c++) {
      const int c2 = c * 2 + hi;
      const int kr0 = l31;
      const int kr1 = 32 + l31;
      bf16x8 kf0 = *(const bf16x8*)(Kc + kr0 * 64 + ((c2 ^ (kr0 & 7)) * 8));
      bf16x8 kf1 = *(const bf16x8*)(Kc + kr1 * 64 + ((c2 ^ (kr1 & 7)) * 8));
      s0 = __builtin_amdgcn_mfma_f32_32x32x16_bf16(kf0, qf[c], s0, 0, 0, 0);
      s1 = __builtin_amdgcn_mfma_f32_32x32x16_bf16(kf1, qf[c], s1, 0, 0, 0);
    }
    __builtin_amdgcn_s_setprio(0);

    float p0[16], p1[16];
    if (k0 + 63 > wmin) {
#pragma unroll
      for (int r = 0; r < 16; r++) {
        int koff = (r & 3) + 8 * (r >> 2) + 4 * hi;
        p0[r] = (k0 + koff <= prow) ? s0[r] : NINF;
        p1[r] = (k0 + 32 + koff <= prow) ? s1[r] : NINF;
      }
    } else {
#pragma unroll
      for (int r = 0; r < 16; r++) { p0[r] = s0[r]; p1[r] = s1[r]; }
    }

    float tm = NINF;
#pragma unroll
    for (int r = 0; r < 16; r++) tm = fmaxf(tm, fmaxf(p0[r], p1[r]));
    tm = fmaxf(tm, __shfl_xor(tm, 32));
    if (__any(tm > m_run + 8.0f)) {
      float mn = fmaxf(fmaxf(m_run, tm), -1e30f);
      float scale = exp2f((m_run - mn) * L2E);
      l_run *= scale;
#pragma unroll
      for (int dt = 0; dt < 2; dt++)
#pragma unroll
        for (int r = 0; r < 16; r++) oT[dt][r] *= scale;
      m_run = mn;
    }
    const float mnl = m_run * L2E;
    float rs = 0.f;
#pragma unroll
    for (int r = 0; r < 16; r++) {
      p0[r] = exp2f(p0[r] * L2E - mnl);
      p1[r] = exp2f(p1[r] * L2E - mnl);
      rs += p0[r] + p1[r];
    }
    rs += __shfl_xor(rs, 32);
    l_run += rs;

#pragma unroll
    for (int kc = 0; kc < 4; kc++) {
      const float* P = (kc < 2) ? p0 : p1;
      const int rb = (kc & 1) * 8;
      uint32_t xa0 = packbf(P[rb + 0], P[rb + 1]);
      uint32_t xa1 = packbf(P[rb + 2], P[rb + 3]);
      uint32_t xb0 = packbf(P[rb + 4], P[rb + 5]);
      uint32_t xb1 = packbf(P[rb + 6], P[rb + 7]);
      uint32_t sa0 = (uint32_t)__shfl_xor((int)xa0, 32);
      uint32_t sa1 = (uint32_t)__shfl_xor((int)xa1, 32);
      uint32_t sb0 = (uint32_t)__shfl_xor((int)xb0, 32);
      uint32_t sb1 = (uint32_t)__shfl_xor((int)xb1, 32);
      union { uint32_t u[4]; bf16x8 v; } pf;
      pf.u[0] = hi ? sb0 : xa0;
      pf.u[1] = hi ? sb1 : xa1;
      pf.u[2] = hi ? xb0 : sa0;
      pf.u[3] = hi ? xb1 : sa1;
      __builtin_amdgcn_s_setprio(1);
#pragma unroll
      for (int dt = 0; dt < 2; dt++) {
        const int vr = dt * 32 + l31;
        const int c2 = kc * 2 + hi;
        bf16x8 vf = *(const bf16x8*)(Vc + vr * 64 + ((c2 ^ (vr & 7)) * 8));
        oT[dt] = __builtin_amdgcn_mfma_f32_32x32x16_bf16(vf, pf.v, oT[dt], 0, 0, 0);
      }
      __builtin_amdgcn_s_setprio(0);
    }

    __syncthreads();
  }

  const float rl = (l_run > 0.f) ? 1.0f / l_run : 0.f;
  bf16_t* Ot = (bf16_t*)Ks + wv * 2048;
#pragma unroll
  for (int dt = 0; dt < 2; dt++)
#pragma unroll
    for (int r = 0; r < 16; r++) {
      int chunk = dt * 4 + (r >> 2);
      int el = (r & 3) + 4 * hi;
      Ot[l31 * 64 + ((chunk ^ (l31 & 7)) * 8) + el] = (__bf16)(oT[dt][r] * rl);
    }
  __syncthreads();
#pragma unroll
  for (int it = 0; it < 4; it++) {
    int qr2 = (lane >> 3) + it * 8;
    int cc = lane & 7;
    bf16x8 v = *(const bf16x8*)(Ot + qr2 * 64 + ((cc ^ (qr2 & 7)) * 8));
    *(bf16x8*)(&O[(size_t)(b * S_ + q0 + wv * 32 + qr2) * D_ + h * 64 + cc * 8]) = v;
  }
}

extern "C" void kernel_launch(void* const* d_in, const int* in_sizes, int n_in,
                              void* d_out, int out_size, void* d_ws, size_t ws_size,
                              hipStream_t stream) {
  const float* inputs = (const float*)d_in[0];
  const int* positions = (const int*)d_in[1];
  const float* W_in = (const float*)d_in[2];
  const float* W_out = (const float*)d_in[3];
  float* out = (float*)d_out;

  bf16_t* X_bf = (bf16_t*)d_ws;
  bf16_t* Win_bf = X_bf + (size_t)4096 * 1024;
  bf16_t* Wout_bf = Win_bf + (size_t)3072 * 1024;
  bf16_t* qkv_bf = Wout_bf + (size_t)1024 * 1024;
  bf16_t* Qb = qkv_bf + (size_t)4096 * 3072;
  bf16_t* Kb = Qb + (size_t)B_ * H_ * S_ * HD_;
  bf16_t* Vtb = Kb + (size_t)B_ * H_ * S_ * HD_;
  bf16_t* Ob = Vtb + (size_t)B_ * H_ * S_ * HD_;

  cast_bf16_kernel<<<dim3(2048), dim3(256), 0, stream>>>(inputs, X_bf, (4096 * 1024) / 4);
  cast_bf16_kernel<<<dim3(2048), dim3(256), 0, stream>>>(W_in, Win_bf, (3072 * 1024) / 4);
  cast_bf16_kernel<<<dim3(1024), dim3(256), 0, stream>>>(W_out, Wout_bf, (1024 * 1024) / 4);

  gemm256<bf16_t><<<dim3(16, 12), dim3(512), 0, stream>>>(X_bf, Win_bf, qkv_bf, 4096, 3072, 1024);

  rope_qk_kernel<<<dim3((B_ * S_ * H_ * 32) / 256), dim3(256), 0, stream>>>(qkv_bf, positions, Qb, Kb);
  v_transpose_kernel<<<dim3(S_ / 64, H_, B_), dim3(256), 0, stream>>>(qkv_bf, Vtb);

  attn_kernel<<<dim3(512), dim3(256), 0, stream>>>(Qb, Kb, Vtb, positions, Ob);

  gemm_bt<float><<<dim3(32, 8), dim3(256), 0, stream>>>(Ob, Wout_bf, out, 4096, 1024, 1024);
}

// Round 11
// 152.938 us; speedup vs baseline: 1.0856x; 1.0469x over previous
//
#include <hip/hip_runtime.h>
#include <stdint.h>
#include <math.h>

#define B_ 2
#define S_ 2048
#define D_ 1024
#define H_ 16
#define HD_ 64
#define KVBLK 64

typedef __bf16 bf16_t;
typedef __bf16 bf16x4 __attribute__((ext_vector_type(4)));
typedef __bf16 bf16x8 __attribute__((ext_vector_type(8)));
typedef float f32x4 __attribute__((ext_vector_type(4)));
typedef float f32x16 __attribute__((ext_vector_type(16)));
typedef float float4v __attribute__((ext_vector_type(4)));

#define L2E 1.4426950408889634f
#define NINF (-__builtin_inff())

__device__ __forceinline__ void gload_lds16(const bf16_t* g, bf16_t* l) {
  __builtin_amdgcn_global_load_lds((const __attribute__((address_space(1))) void*)g,
                                   (__attribute__((address_space(3))) void*)l, 16, 0, 0);
}

__device__ __forceinline__ uint32_t packbf(float a, float b) {
  union { __bf16 h[2]; uint32_t u; } cvt;
  cvt.h[0] = (__bf16)a; cvt.h[1] = (__bf16)b;
  return cvt.u;
}

// ---------------- fused cast f32 -> bf16 for all three inputs (vector x4) ----------------
__global__ void cast3_bf16_kernel(const float* __restrict__ s0, bf16_t* __restrict__ d0, int n0,
                                  const float* __restrict__ s1, bf16_t* __restrict__ d1, int n1,
                                  const float* __restrict__ s2, bf16_t* __restrict__ d2, int n2) {
  int i = blockIdx.x * blockDim.x + threadIdx.x;
  int stride = gridDim.x * blockDim.x;
  int tot = n0 + n1 + n2;
  for (; i < tot; i += stride) {
    const float* s; bf16_t* d; int j = i;
    if (j < n0) { s = s0; d = d0; }
    else if ((j -= n0) < n1) { s = s1; d = d1; }
    else { j -= n1; s = s2; d = d2; }
    float4v f = *(const float4v*)(s + (size_t)j * 4);
    bf16x4 o;
    o[0] = (__bf16)f[0]; o[1] = (__bf16)f[1]; o[2] = (__bf16)f[2]; o[3] = (__bf16)f[3];
    *(bf16x4*)(d + (size_t)j * 4) = o;
  }
}

// ---------------- small GEMM (128^2, m97 structure) for gemm2 ----------------
template <typename OutT>
__global__ __launch_bounds__(256) void gemm_bt(const bf16_t* __restrict__ A,
                                               const bf16_t* __restrict__ Bm,
                                               OutT* __restrict__ C,
                                               int M, int N, int K) {
  __shared__ bf16_t As[128 * 32];
  __shared__ bf16_t Bs[128 * 32];
  const int t = threadIdx.x;
  const int lane = t & 63, wave = t >> 6;
  const int wr = wave >> 1, wc = wave & 1;
  const int qr = lane & 15, g = lane >> 4;
  const int bm = blockIdx.x, bn = blockIdx.y;

  f32x4 acc[4][4];
#pragma unroll
  for (int m = 0; m < 4; m++)
#pragma unroll
    for (int n = 0; n < 4; n++) acc[m][n] = (f32x4){0.f, 0.f, 0.f, 0.f};

  const bf16_t* Abase = A + (size_t)(bm * 128) * K;
  const bf16_t* Bbase = Bm + (size_t)(bn * 128) * K;
  const int srow = t >> 2;
  const int scol = (t & 3) * 8;

  for (int kk = 0; kk < K; kk += 32) {
    gload_lds16(Abase + (size_t)srow * K + kk + scol,        As + t * 8);
    gload_lds16(Abase + (size_t)(srow + 64) * K + kk + scol, As + 2048 + t * 8);
    gload_lds16(Bbase + (size_t)srow * K + kk + scol,        Bs + t * 8);
    gload_lds16(Bbase + (size_t)(srow + 64) * K + kk + scol, Bs + 2048 + t * 8);
    __syncthreads();
    bf16x8 a[4], b[4];
#pragma unroll
    for (int m = 0; m < 4; m++)
      a[m] = *(const bf16x8*)(As + (wr * 64 + m * 16 + qr) * 32 + g * 8);
#pragma unroll
    for (int n = 0; n < 4; n++)
      b[n] = *(const bf16x8*)(Bs + (wc * 64 + n * 16 + qr) * 32 + g * 8);
#pragma unroll
    for (int m = 0; m < 4; m++)
#pragma unroll
      for (int n = 0; n < 4; n++)
        acc[m][n] = __builtin_amdgcn_mfma_f32_16x16x32_bf16(a[m], b[n], acc[m][n], 0, 0, 0);
    __syncthreads();
  }

#pragma unroll
  for (int m = 0; m < 4; m++) {
    int row0 = bm * 128 + wr * 64 + m * 16 + g * 4;
#pragma unroll
    for (int n = 0; n < 4; n++) {
      int col = bn * 128 + wc * 64 + n * 16 + qr;
#pragma unroll
      for (int r = 0; r < 4; r++)
        C[(size_t)(row0 + r) * N + col] = (OutT)acc[m][n][r];
    }
  }
}

// ---------------- big GEMM: 256^2 tile, BK=64, 8-wave, phase-pipelined (T3+T4+T5) ----------------
// Region-read map (A tile rows): ph0 reads regions {0,2} (alo), ph2 reads {1,3} (ahi);
// B all read by end of ph1. Stage T+2: ph1 A{0,2}, ph2 B all, ph3 A{1,3} (race-proven, R10).
// Gate: counted vmcnt(8) -- tile T's 8 loads complete, tile T+1's 8 stay in flight (m218).
template <typename OutT>
__global__ __launch_bounds__(512, 2) void gemm256(const bf16_t* __restrict__ A,
                                                  const bf16_t* __restrict__ Bm,
                                                  OutT* __restrict__ C,
                                                  int M, int N, int K) {
  __shared__ bf16_t As[2][256 * 64];
  __shared__ bf16_t Bs[2][256 * 64];
  const int t = threadIdx.x;
  const int lane = t & 63, wid = t >> 6;
  const int qr = lane & 15, g = lane >> 4;
  const int wm = wid >> 2, wn = wid & 3;
  const int bm = blockIdx.x, bn = blockIdx.y;
  const int NT = K >> 6;

  const bf16_t* Ab = A + (size_t)(bm * 256) * K;
  const bf16_t* Bb = Bm + (size_t)(bn * 256) * K;

  const bf16_t* srcA[4];
  const bf16_t* srcB[4];
  int ldsOff[4];
#pragma unroll
  for (int i = 0; i < 4; i++) {
    int e = t + 512 * i;
    int row = e >> 3, cs = e & 7;
    int gcol = (cs ^ (row & 7)) * 8;
    srcA[i] = Ab + (size_t)row * K + gcol;
    srcB[i] = Bb + (size_t)row * K + gcol;
    ldsOff[i] = e * 8;
  }

  f32x4 acc[8][4];
#pragma unroll
  for (int m = 0; m < 8; m++)
#pragma unroll
    for (int n = 0; n < 4; n++) acc[m][n] = (f32x4){0.f, 0.f, 0.f, 0.f};

#define RD(buf_, r_, k_) (*(const bf16x8*)((buf_) + (r_) * 64 + ((((k_) * 4 + g) ^ ((r_) & 7)) * 8)))

#pragma unroll
  for (int i = 0; i < 4; i++) gload_lds16(srcA[i], As[0] + ldsOff[i]);
#pragma unroll
  for (int i = 0; i < 4; i++) gload_lds16(srcB[i], Bs[0] + ldsOff[i]);
#pragma unroll
  for (int i = 0; i < 4; i++) gload_lds16(srcA[i] + 64, As[1] + ldsOff[i]);
#pragma unroll
  for (int i = 0; i < 4; i++) gload_lds16(srcB[i] + 64, Bs[1] + ldsOff[i]);

  for (int T = 0; T < NT; ++T) {
    bf16_t* A_c = As[T & 1];
    bf16_t* B_c = Bs[T & 1];
    if (T + 1 < NT) asm volatile("s_waitcnt vmcnt(8)" ::: "memory");
    else            asm volatile("s_waitcnt vmcnt(0)" ::: "memory");
    __builtin_amdgcn_sched_barrier(0);
    __builtin_amdgcn_s_barrier();

    const bool st = (T + 2 < NT);
    const int kt2 = (T + 2) * 64;

    bf16x8 alo[4][2], ahi[4][2], bfr[4][2];

    // ---- ph0 ----
#pragma unroll
    for (int m = 0; m < 4; m++) {
      int r = wm * 128 + m * 16 + qr;
      alo[m][0] = RD(A_c, r, 0); alo[m][1] = RD(A_c, r, 1);
    }
#pragma unroll
    for (int n = 0; n < 2; n++) {
      int r = wn * 64 + n * 16 + qr;
      bfr[n][0] = RD(B_c, r, 0); bfr[n][1] = RD(B_c, r, 1);
    }
    __builtin_amdgcn_s_barrier();
    __builtin_amdgcn_s_setprio(1);
#pragma unroll
    for (int m = 0; m < 4; m++)
#pragma unroll
      for (int n = 0; n < 2; n++)
#pragma unroll
        for (int k = 0; k < 2; k++)
          acc[m][n] = __builtin_amdgcn_mfma_f32_16x16x32_bf16(alo[m][k], bfr[n][k], acc[m][n], 0, 0, 0);
    __builtin_amdgcn_s_setprio(0);
    __builtin_amdgcn_s_barrier();

    // ---- ph1 ----
#pragma unroll
    for (int n = 2; n < 4; n++) {
      int r = wn * 64 + n * 16 + qr;
      bfr[n][0] = RD(B_c, r, 0); bfr[n][1] = RD(B_c, r, 1);
    }
    if (st) {
      gload_lds16(srcA[0] + kt2, A_c + ldsOff[0]);
      gload_lds16(srcA[2] + kt2, A_c + ldsOff[2]);
    }
    __builtin_amdgcn_s_barrier();
    __builtin_amdgcn_s_setprio(1);
#pragma unroll
    for (int m = 0; m < 4; m++)
#pragma unroll
      for (int n = 2; n < 4; n++)
#pragma unroll
        for (int k = 0; k < 2; k++)
          acc[m][n] = __builtin_amdgcn_mfma_f32_16x16x32_bf16(alo[m][k], bfr[n][k], acc[m][n], 0, 0, 0);
    __builtin_amdgcn_s_setprio(0);
    __builtin_amdgcn_s_barrier();

    // ---- ph2 ----
#pragma unroll
    for (int m = 0; m < 4; m++) {
      int r = wm * 128 + (m + 4) * 16 + qr;
      ahi[m][0] = RD(A_c, r, 0); ahi[m][1] = RD(A_c, r, 1);
    }
    if (st) {
      gload_lds16(srcB[0] + kt2, B_c + ldsOff[0]);
      gload_lds16(srcB[1] + kt2, B_c + ldsOff[1]);
      gload_lds16(srcB[2] + kt2, B_c + ldsOff[2]);
      gload_lds16(srcB[3] + kt2, B_c + ldsOff[3]);
    }
    __builtin_amdgcn_s_barrier();
    __builtin_amdgcn_s_setprio(1);
#pragma unroll
    for (int m = 0; m < 4; m++)
#pragma unroll
      for (int n = 0; n < 2; n++)
#pragma unroll
        for (int k = 0; k < 2; k++)
          acc[m + 4][n] = __builtin_amdgcn_mfma_f32_16x16x32_bf16(ahi[m][k], bfr[n][k], acc[m + 4][n], 0, 0, 0);
    __builtin_amdgcn_s_setprio(0);
    __builtin_amdgcn_s_barrier();

    // ---- ph3 ----
    if (st) {
      gload_lds16(srcA[1] + kt2, A_c + ldsOff[1]);
      gload_lds16(srcA[3] + kt2, A_c + ldsOff[3]);
    }
    __builtin_amdgcn_s_barrier();
    __builtin_amdgcn_s_setprio(1);
#pragma unroll
    for (int m = 0; m < 4; m++)
#pragma unroll
      for (int n = 2; n < 4; n++)
#pragma unroll
        for (int k = 0; k < 2; k++)
          acc[m + 4][n] = __builtin_amdgcn_mfma_f32_16x16x32_bf16(ahi[m][k], bfr[n][k], acc[m + 4][n], 0, 0, 0);
    __builtin_amdgcn_s_setprio(0);
    __builtin_amdgcn_s_barrier();
  }
#undef RD

#pragma unroll
  for (int m = 0; m < 8; m++) {
    int row0 = bm * 256 + wm * 128 + m * 16 + g * 4;
#pragma unroll
    for (int n = 0; n < 4; n++) {
      int col = bn * 256 + wn * 64 + n * 16 + qr;
#pragma unroll
      for (int r = 0; r < 4; r++)
        C[(size_t)(row0 + r) * N + col] = (OutT)acc[m][n][r];
    }
  }
}

// ---------------- RoPE on q,k + q-scale; writes Q,K as [B][H][S][HD] bf16 ----------------
__global__ void rope_qk_kernel(const bf16_t* __restrict__ qkv, const int* __restrict__ pos,
                               bf16_t* __restrict__ Q, bf16_t* __restrict__ Ko) {
  int idx = blockIdx.x * blockDim.x + threadIdx.x;
  if (idx >= B_ * S_ * H_ * 32) return;
  int i = idx & 31;
  int h = (idx >> 5) & (H_ - 1);
  int bs = idx >> 9;
  const bf16_t* row = qkv + (size_t)bs * (3 * D_) + h * 192;
  float q1 = (float)row[i], q2 = (float)row[i + 32];
  float k1 = (float)row[64 + i], k2 = (float)row[96 + i];
  int p = pos[bs];
  float inv = exp2f(-(float)i * (13.287712379549449f / 32.0f));
  float ang = (float)p * inv;
  float sn, cs;
  sincosf(ang, &sn, &cs);
  float qo1 = (q1 * cs - q2 * sn) * 0.125f;
  float qo2 = (q2 * cs + q1 * sn) * 0.125f;
  float ko1 = k1 * cs - k2 * sn;
  float ko2 = k2 * cs + k1 * sn;
  int b = bs >> 11, s = bs & (S_ - 1);
  size_t o = ((size_t)(b * H_ + h) * S_ + s) * HD_ + i;
  Q[o] = (__bf16)qo1;  Q[o + 32] = (__bf16)qo2;
  Ko[o] = (__bf16)ko1; Ko[o + 32] = (__bf16)ko2;
}

// ---------------- V transpose: qkv v-slice -> Vt [B][H][HD][S] bf16 ----------------
__global__ __launch_bounds__(256) void v_transpose_kernel(const bf16_t* __restrict__ qkv,
                                                          bf16_t* __restrict__ Vt) {
  __shared__ bf16_t tile[64][72];
  int t = threadIdx.x;
  int s0 = blockIdx.x * 64;
  int h = blockIdx.y, b = blockIdx.z;
  int sl = t >> 4;
  int cb = (t & 15) * 4;
#pragma unroll
  for (int it = 0; it < 4; it++) {
    int s = sl + it * 16;
    const bf16_t* src = qkv + (size_t)(b * S_ + s0 + s) * (3 * D_) + h * 192 + 128 + cb;
    bf16x4 v = *(const bf16x4*)src;
    tile[cb + 0][s] = v[0]; tile[cb + 1][s] = v[1];
    tile[cb + 2][s] = v[2]; tile[cb + 3][s] = v[3];
  }
  __syncthreads();
#pragma unroll
  for (int it = 0; it < 4; it++) {
    int d = sl + it * 16;
    bf16x4 v;
    v[0] = tile[d][cb]; v[1] = tile[d][cb + 1]; v[2] = tile[d][cb + 2]; v[3] = tile[d][cb + 3];
    *(bf16x4*)(Vt + ((size_t)((b * H_ + h) * HD_ + d)) * S_ + s0 + cb) = v;
  }
}

// ---------------- flash attention: split-KV (2 halves) + XCD-resident KV mapping ----------------
// Grid 1024, 256 thr = 4 waves. bid = [v:5][bhsub:2][xcd:3]; bh=(bid&7)*4+((bid>>3)&3);
// v=bid>>5: qblk=15-(v>>1), half=v&1. Each block processes kv tiles [half*16, min(nt,half*16+16)).
// nt<=16 (no half1 work anywhere in block): direct final write (today's path; half1 block exits).
// nt>16: both halves write unnormalized bf16 partial O + (m,l) stats; merge kernel combines.
__global__ __launch_bounds__(256) void attn_kernel(const bf16_t* __restrict__ Q,
                                                   const bf16_t* __restrict__ K,
                                                   const bf16_t* __restrict__ Vt,
                                                   const int* __restrict__ pos,
                                                   bf16_t* __restrict__ O,
                                                   bf16_t* __restrict__ Opart,
                                                   float* __restrict__ Mst,
                                                   float* __restrict__ Lst) {
  __shared__ bf16_t Ks[2][64 * 64];
  __shared__ bf16_t Vs[2][64 * 64];

  const int t = threadIdx.x;
  const int lane = t & 63, wv = t >> 6;
  const int l31 = lane & 31, hi = lane >> 5;

  const int bid = blockIdx.x;
  const int bh = (bid & 7) * 4 + ((bid >> 3) & 3);
  const int v5 = bid >> 5;
  const int qblk = 15 - (v5 >> 1);
  const int half = v5 & 1;
  const int b = bh >> 4, h = bh & 15;
  const int q0 = qblk * 128;

  const bf16_t* Qb = Q + (size_t)bh * (S_ * HD_);
  const bf16_t* Kb = K + (size_t)bh * (S_ * HD_);
  const bf16_t* Vb = Vt + (size_t)bh * (HD_ * S_);

  const int qrow = q0 + wv * 32 + l31;

  const int prow = pos[b * S_ + qrow];
  int wmin = prow;
#pragma unroll
  for (int off = 1; off < 32; off <<= 1) wmin = min(wmin, __shfl_xor(wmin, off));

  int mp = max(pos[b * S_ + q0 + lane], pos[b * S_ + q0 + 64 + lane]);
#pragma unroll
  for (int off = 1; off < 64; off <<= 1) mp = max(mp, __shfl_xor(mp, off));
  const int nt = min(S_ / KVBLK, (mp >> 6) + 1);

  const int t0 = half * 16;
  const int t1 = min(nt, t0 + 16);
  if (t0 >= t1) return;                 // uniform for whole block (nt is block-wide)
  const bool needs_merge = (nt > 16);

  bf16x8 qf[4];
#pragma unroll
  for (int c = 0; c < 4; c++)
    qf[c] = *(const bf16x8*)(Qb + (size_t)qrow * HD_ + c * 16 + hi * 8);

  const int r0 = t >> 3, c0 = t & 7;
  const int r1 = (t + 256) >> 3, c1 = t & 7;
  const bf16_t* KgA = Kb + (size_t)r0 * HD_ + ((c0 ^ (r0 & 7)) * 8);
  const bf16_t* KgB = Kb + (size_t)r1 * HD_ + ((c1 ^ (r1 & 7)) * 8);
  const bf16_t* VgA = Vb + (size_t)r0 * S_ + ((c0 ^ (r0 & 7)) * 8);
  const bf16_t* VgB = Vb + (size_t)r1 * S_ + ((c1 ^ (r1 & 7)) * 8);
  const int ldsA = t * 8, ldsB = (t + 256) * 8;

  f32x16 oT[2];
#pragma unroll
  for (int dt = 0; dt < 2; dt++)
#pragma unroll
    for (int r = 0; r < 16; r++) oT[dt][r] = 0.f;
  float m_run = NINF, l_run = 0.f;

  // prologue: stage tile t0 into buf 0 (t0 is 0 or 16, both even -> cur=kt&1 starts at 0)
  {
    const int kn = t0 * KVBLK;
    gload_lds16(KgA + (size_t)kn * HD_, Ks[0] + ldsA);
    gload_lds16(KgB + (size_t)kn * HD_, Ks[0] + ldsB);
    gload_lds16(VgA + kn, Vs[0] + ldsA);
    gload_lds16(VgB + kn, Vs[0] + ldsB);
  }
  __syncthreads();

  for (int kt = t0; kt < t1; ++kt) {
    const int k0 = kt * KVBLK;
    const int cur = kt & 1;
    if (kt + 1 < t1) {
      const int kn = (kt + 1) * KVBLK;
      gload_lds16(KgA + (size_t)kn * HD_, Ks[cur ^ 1] + ldsA);
      gload_lds16(KgB + (size_t)kn * HD_, Ks[cur ^ 1] + ldsB);
      gload_lds16(VgA + kn, Vs[cur ^ 1] + ldsA);
      gload_lds16(VgB + kn, Vs[cur ^ 1] + ldsB);
    }
    const bf16_t* Kc = Ks[cur];
    const bf16_t* Vc = Vs[cur];

    f32x16 s0, s1;
#pragma unroll
    for (int r = 0; r < 16; r++) { s0[r] = 0.f; s1[r] = 0.f; }
    __builtin_amdgcn_s_setprio(1);
#pragma unroll
    for (int c = 0; c < 4; c++) {
      const int c2 = c * 2 + hi;
      const int kr0 = l31;
      const int kr1 = 32 + l31;
      bf16x8 kf0 = *(const bf16x8*)(Kc + kr0 * 64 + ((c2 ^ (kr0 & 7)) * 8));
      bf16x8 kf1 = *(const bf16x8*)(Kc + kr1 * 64 + ((c2 ^ (kr1 & 7)) * 8));
      s0 = __builtin_amdgcn_mfma_f32_32x32x16_bf16(kf0, qf[c], s0, 0, 0, 0);
      s1 = __builtin_amdgcn_mfma_f32_32x32x16_bf16(kf1, qf[c], s1, 0, 0, 0);
    }
    __builtin_amdgcn_s_setprio(0);

    float p0[16], p1[16];
    if (k0 + 63 > wmin) {
#pragma unroll
      for (int r = 0; r < 16; r++) {
        int koff = (r & 3) + 8 * (r >> 2) + 4 * hi;
        p0[r] = (k0 + koff <= prow) ? s0[r] : NINF;
        p1[r] = (k0 + 32 + koff <= prow) ? s1[r] : NINF;
      }
    } else {
#pragma unroll
      for (int r = 0; r < 16; r++) { p0[r] = s0[r]; p1[r] = s1[r]; }
    }

    float tm = NINF;
#pragma unroll
    for (int r = 0; r < 16; r++) tm = fmaxf(tm, fmaxf(p0[r], p1[r]));
    tm = fmaxf(tm, __shfl_xor(tm, 32));
    if (__any(tm > m_run + 8.0f)) {
      float mn = fmaxf(fmaxf(m_run, tm), -1e30f);
      float scale = exp2f((m_run - mn) * L2E);
      l_run *= scale;
#pragma unroll
      for (int dt = 0; dt < 2; dt++)
#pragma unroll
        for (int r = 0; r < 16; r++) oT[dt][r] *= scale;
      m_run = mn;
    }
    // NaN guard: if this wave's rows are entirely masked so far (m_run still -inf),
    // exp2(-inf - -inf) would be NaN; clamp so all-masked p -> exp2(-inf) = 0.
    const float mnl = (m_run == NINF) ? 3.0e38f : m_run * L2E;
    float rs = 0.f;
#pragma unroll
    for (int r = 0; r < 16; r++) {
      p0[r] = exp2f(p0[r] * L2E - mnl);
      p1[r] = exp2f(p1[r] * L2E - mnl);
      rs += p0[r] + p1[r];
    }
    rs += __shfl_xor(rs, 32);
    l_run += rs;

#pragma unroll
    for (int kc = 0; kc < 4; kc++) {
      const float* P = (kc < 2) ? p0 : p1;
      const int rb = (kc & 1) * 8;
      uint32_t xa0 = packbf(P[rb + 0], P[rb + 1]);
      uint32_t xa1 = packbf(P[rb + 2], P[rb + 3]);
      uint32_t xb0 = packbf(P[rb + 4], P[rb + 5]);
      uint32_t xb1 = packbf(P[rb + 6], P[rb + 7]);
      uint32_t sa0 = (uint32_t)__shfl_xor((int)xa0, 32);
      uint32_t sa1 = (uint32_t)__shfl_xor((int)xa1, 32);
      uint32_t sb0 = (uint32_t)__shfl_xor((int)xb0, 32);
      uint32_t sb1 = (uint32_t)__shfl_xor((int)xb1, 32);
      union { uint32_t u[4]; bf16x8 v; } pf;
      pf.u[0] = hi ? sb0 : xa0;
      pf.u[1] = hi ? sb1 : xa1;
      pf.u[2] = hi ? xb0 : sa0;
      pf.u[3] = hi ? xb1 : sa1;
      __builtin_amdgcn_s_setprio(1);
#pragma unroll
      for (int dt = 0; dt < 2; dt++) {
        const int vr = dt * 32 + l31;
        const int c2 = kc * 2 + hi;
        bf16x8 vf = *(const bf16x8*)(Vc + vr * 64 + ((c2 ^ (vr & 7)) * 8));
        oT[dt] = __builtin_amdgcn_mfma_f32_32x32x16_bf16(vf, pf.v, oT[dt], 0, 0, 0);
      }
      __builtin_amdgcn_s_setprio(0);
    }

    __syncthreads();
  }

  // epilogue: O^T (regs) -> LDS transpose -> coalesced stores.
  // needs_merge: store UNNORMALIZED partial (rl=1) + stats; else normalize and store final.
  const float rl = needs_merge ? 1.0f : ((l_run > 0.f) ? 1.0f / l_run : 0.f);
  bf16_t* Ot = (bf16_t*)Ks + wv * 2048;
#pragma unroll
  for (int dt = 0; dt < 2; dt++)
#pragma unroll
    for (int r = 0; r < 16; r++) {
      int chunk = dt * 4 + (r >> 2);
      int el = (r & 3) + 4 * hi;
      Ot[l31 * 64 + ((chunk ^ (l31 & 7)) * 8) + el] = (__bf16)(oT[dt][r] * rl);
    }
  __syncthreads();
  if (needs_merge) {
    bf16_t* dst = Opart + (((size_t)(half * 32 + bh) * 16 + qblk) * 128) * 64;
#pragma unroll
    for (int it = 0; it < 4; it++) {
      int qr2 = (lane >> 3) + it * 8;
      int cc = lane & 7;
      bf16x8 vv = *(const bf16x8*)(Ot + qr2 * 64 + ((cc ^ (qr2 & 7)) * 8));
      *(bf16x8*)(&dst[(size_t)(wv * 32 + qr2) * 64 + cc * 8]) = vv;
    }
    if (hi == 0) {
      size_t sidx = ((size_t)(half * 32 + bh) * 16 + qblk) * 128 + wv * 32 + l31;
      Mst[sidx] = m_run;
      Lst[sidx] = l_run;
    }
  } else {
#pragma unroll
    for (int it = 0; it < 4; it++) {
      int qr2 = (lane >> 3) + it * 8;
      int cc = lane & 7;
      bf16x8 vv = *(const bf16x8*)(Ot + qr2 * 64 + ((cc ^ (qr2 & 7)) * 8));
      *(bf16x8*)(&O[(size_t)(b * S_ + q0 + wv * 32 + qr2) * D_ + h * 64 + cc * 8]) = vv;
    }
  }
}

// ---------------- split-KV merge: O = (O0*w0 + O1*w1) / (l0*w0 + l1*w1) ----------------
// Grid 512 (same XCD mapping as attn, halves' partials are L2-local). Recomputes nt from pos;
// exits where attn wrote final O directly (nt<=16) -- deterministic agreement with attn.
__global__ __launch_bounds__(256) void attn_merge_kernel(const bf16_t* __restrict__ Opart,
                                                         const float* __restrict__ Mst,
                                                         const float* __restrict__ Lst,
                                                         const int* __restrict__ pos,
                                                         bf16_t* __restrict__ O) {
  __shared__ int wmax_s[4];
  const int t = threadIdx.x;
  const int bid = blockIdx.x;
  const int bh = (bid & 7) * 4 + ((bid >> 3) & 3);
  const int qblk = 15 - (bid >> 5);
  const int b = bh >> 4, h = bh & 15;
  const int q0 = qblk * 128;

  int p = pos[b * S_ + q0 + (t & 127)];
#pragma unroll
  for (int off = 1; off < 64; off <<= 1) p = max(p, __shfl_xor(p, off));
  if ((t & 63) == 0) wmax_s[t >> 6] = p;
  __syncthreads();
  int mp = max(max(wmax_s[0], wmax_s[1]), max(wmax_s[2], wmax_s[3]));
  if ((mp >> 6) + 1 <= 16) return;   // attn wrote final O directly

  const int r = t >> 1, dh = (t & 1) * 32;
  const size_t s0i = ((size_t)(0 * 32 + bh) * 16 + qblk) * 128 + r;
  const size_t s1i = ((size_t)(1 * 32 + bh) * 16 + qblk) * 128 + r;
  float m0 = Mst[s0i], l0 = Lst[s0i];
  float m1 = Mst[s1i], l1 = Lst[s1i];
  float m = fmaxf(fmaxf(m0, m1), -1e30f);
  float w0 = exp2f((m0 - m) * L2E);
  float w1 = exp2f((m1 - m) * L2E);
  float lt = l0 * w0 + l1 * w1;
  float rl = (lt > 0.f) ? 1.0f / lt : 0.f;
  w0 *= rl; w1 *= rl;
  const bf16_t* pa = Opart + s0i * 64 + dh;
  const bf16_t* pb = Opart + s1i * 64 + dh;
  bf16_t* dst = O + (size_t)(b * S_ + q0 + r) * D_ + h * 64 + dh;
#pragma unroll
  for (int c = 0; c < 4; c++) {
    bf16x8 a = *(const bf16x8*)(pa + c * 8);
    bf16x8 bb = *(const bf16x8*)(pb + c * 8);
    bf16x8 o;
#pragma unroll
    for (int j = 0; j < 8; j++)
      o[j] = (__bf16)((float)a[j] * w0 + (float)bb[j] * w1);
    *(bf16x8*)(dst + c * 8) = o;
  }
}

extern "C" void kernel_launch(void* const* d_in, const int* in_sizes, int n_in,
                              void* d_out, int out_size, void* d_ws, size_t ws_size,
                              hipStream_t stream) {
  const float* inputs = (const float*)d_in[0];
  const int* positions = (const int*)d_in[1];
  const float* W_in = (const float*)d_in[2];
  const float* W_out = (const float*)d_in[3];
  float* out = (float*)d_out;

  bf16_t* X_bf = (bf16_t*)d_ws;
  bf16_t* Win_bf = X_bf + (size_t)4096 * 1024;
  bf16_t* Wout_bf = Win_bf + (size_t)3072 * 1024;
  bf16_t* qkv_bf = Wout_bf + (size_t)1024 * 1024;
  bf16_t* Qb = qkv_bf + (size_t)4096 * 3072;
  bf16_t* Kb = Qb + (size_t)B_ * H_ * S_ * HD_;
  bf16_t* Vtb = Kb + (size_t)B_ * H_ * S_ * HD_;
  bf16_t* Ob = Vtb + (size_t)B_ * H_ * S_ * HD_;

  // split-KV partial buffers alias qkv_bf (dead after rope/v_transpose; fully
  // rewritten by gemm256 each launch -> deterministic across graph replays).
  // Opart: 2*32*16*128*64 bf16 = 16.8MB; stats 2*32*16*128 f32 x2 = 1MB; qkv = 25.2MB. Fits.
  bf16_t* Opart = qkv_bf;
  float* Mst = (float*)(qkv_bf + (size_t)2 * 32 * 16 * 128 * 64);
  float* Lst = Mst + (size_t)2 * 32 * 16 * 128;

  cast3_bf16_kernel<<<dim3(2048), dim3(256), 0, stream>>>(
      inputs, X_bf, (4096 * 1024) / 4,
      W_in, Win_bf, (3072 * 1024) / 4,
      W_out, Wout_bf, (1024 * 1024) / 4);

  gemm256<bf16_t><<<dim3(16, 12), dim3(512), 0, stream>>>(X_bf, Win_bf, qkv_bf, 4096, 3072, 1024);

  rope_qk_kernel<<<dim3((B_ * S_ * H_ * 32) / 256), dim3(256), 0, stream>>>(qkv_bf, positions, Qb, Kb);
  v_transpose_kernel<<<dim3(S_ / 64, H_, B_), dim3(256), 0, stream>>>(qkv_bf, Vtb);

  attn_kernel<<<dim3(1024), dim3(256), 0, stream>>>(Qb, Kb, Vtb, positions, Ob, Opart, Mst, Lst);
  attn_merge_kernel<<<dim3(512), dim3(256), 0, stream>>>(Opart, Mst, Lst, positions, Ob);

  gemm_bt<float><<<dim3(32, 8), dim3(256), 0, stream>>>(Ob, Wout_bf, out, 4096, 1024, 1024);
}